// Round 9
// baseline (215.665 us; speedup 1.0000x reference)
//
#include <hip/hip_runtime.h>
#include <hip/hip_bf16.h>

typedef __bf16 bf16;
typedef __attribute__((ext_vector_type(8))) __bf16 bf16x8;
typedef __attribute__((ext_vector_type(4))) __bf16 bf16x4;
typedef __attribute__((ext_vector_type(4))) float f32x4;

#define BAR() __builtin_amdgcn_s_barrier()

__device__ __forceinline__ void async_load16(const void* g, void* l) {
    __builtin_amdgcn_global_load_lds(
        (const __attribute__((address_space(1))) void*)g,
        (__attribute__((address_space(3))) void*)l, 16, 0, 0);
}

// ---------- kernel 1: per-block partial sum of |w| (deterministic tree) ----------
__global__ __launch_bounds__(256) void k_abs_part(const float* __restrict__ w, int n,
                                                  double* __restrict__ part) {
    __shared__ double sd[256];
    const int per_block = n / gridDim.x;
    const int base = blockIdx.x * per_block;
    double s = 0.0;
    for (int i = threadIdx.x; i < per_block; i += 256)
        s += (double)fabsf(w[base + i]);
    sd[threadIdx.x] = s;
    __syncthreads();
    for (int off = 128; off > 0; off >>= 1) {
        if (threadIdx.x < off) sd[threadIdx.x] += sd[threadIdx.x + off];
        __syncthreads();
    }
    if (threadIdx.x == 0) part[blockIdx.x] = sd[0];
}

// ---------- kernel 2: finalize delta locally + quantize W to ternary bf16 ----------
__global__ __launch_bounds__(256) void k_quantW(const float* __restrict__ w,
                                                const double* __restrict__ part,
                                                bf16* __restrict__ wt, int n4, int wn) {
    __shared__ double sd[256];
    sd[threadIdx.x] = part[threadIdx.x];
    __syncthreads();
    for (int off = 128; off > 0; off >>= 1) {
        if (threadIdx.x < off) sd[threadIdx.x] += sd[threadIdx.x + off];
        __syncthreads();
    }
    const float d = (float)(0.7 * sd[0] / (double)wn);
    const int stride = gridDim.x * 256;
    for (int i = blockIdx.x * 256 + threadIdx.x; i < n4; i += stride) {
        const float4 v = ((const float4*)w)[i];
        bf16x4 o;
        o[0] = (bf16)((v.x > d) ? 1.0f : (v.x < -d) ? -1.0f : 0.0f);
        o[1] = (bf16)((v.y > d) ? 1.0f : (v.y < -d) ? -1.0f : 0.0f);
        o[2] = (bf16)((v.z > d) ? 1.0f : (v.z < -d) ? -1.0f : 0.0f);
        o[3] = (bf16)((v.w > d) ? 1.0f : (v.w < -d) ? -1.0f : 0.0f);
        *(bf16x4*)(wt + (size_t)i * 4) = o;
    }
}

// ---------- helper: stage one 128x64 bf16 B-half via global_load_lds, 256 thr ----------
// Linear LDS dest; swizzle via inverse-permuted GLOBAL source slot s = (c&7)^((t>>3)&7)
// (valid since rows advance by 32 per r-step: (c>>3)&7 == (t>>3)&7).
__device__ __forceinline__ void stage_B128(const bf16* __restrict__ srch, int K, int kt,
                                           char* dst, int t) {
    #pragma unroll
    for (int r = 0; r < 4; ++r) {
        const int c  = (r << 8) + t;              // 1024 chunks of 16B
        const int rp = c >> 3;
        const int s  = (c & 7) ^ ((t >> 3) & 7);
        async_load16(srch + (size_t)rp * K + (kt << 6) + (s << 3), dst + (c << 4));
    }
}

// ---------- kernel 3: fused fp32-A GEMM.  BM=64 x BN=256, 256 thr = 4 waves, ----------
// 4 blocks/CU (LDS 40KB, <=128 regs).  C[m][n] = alpha*sum_k A[m][k]*Wt[n][k] + bias[n].
// A: fp32 global -> 8-reg window -> cvt bf16 -> swizzled ds_write (2 chunks/thread/tile).
// B: bf16 wt via global_load_lds (linear dest + pre-swizzled source).
// 2-phase/K-tile: {RD ks0, MFMA ks0, RD ks1, lgkm+BAR | WA0, LA1, SB(8), MFMA ks1,
// WA1(vmcnt<=8: SB in flight), vmcnt0+lgkm+BAR}.  16 waves/CU hide the drains.
__global__ __launch_bounds__(256, 4) void k_gemmF(const float* __restrict__ Afp,
                                                  const bf16* __restrict__ Bw,
                                                  const float* __restrict__ alphap,
                                                  const float* __restrict__ bias,
                                                  float* __restrict__ C,
                                                  int M, int N, int K) {
    __shared__ __align__(16) char As[8192];      // 64 x 64 bf16, swizzled
    __shared__ __align__(16) char Bs[32768];     // 256 x 64 bf16, swizzled

    const int t    = threadIdx.x;
    const int lane = t & 63;
    const int wn   = t >> 6;          // wave n-quad: cols wn*64..+63
    const int lr   = lane & 15;
    const int hi   = lane >> 4;

    // XCD-chunked, n-fastest: 4 n-siblings of an m-panel co-resident on one XCD
    // -> fp32 A panel read from HBM once, siblings hit L2.
    const int nbn = N >> 8;                       // 4 n-tiles
    const int cpx = gridDim.x >> 3;
    const int lid = (blockIdx.x & 7) * cpx + (blockIdx.x >> 3);
    const int bn0 = (lid % nbn) << 8;
    const int bm0 = (lid / nbn) << 6;             // BM = 64

    const int a_r = t >> 2;                       // A-stage: row (64 rows, 4 thr/row)
    const int a_q = t & 3;                        // 16-elem quarter of the row
    const float* Asrc  = Afp + (size_t)(bm0 + a_r) * K + (a_q << 4);
    const bf16*  Bsrc0 = Bw + (size_t)bn0 * K;
    const bf16*  Bsrc1 = Bw + (size_t)(bn0 + 128) * K;

    f32x4 acc[4][4] = {};
    bf16x8 af[4], bf[4];
    float4 s0, s1;                                // single 8-reg staging window

    const int x0 = ((hi ^ (lr & 7)) << 4);
    const int x1 = (((4 + hi) ^ (lr & 7)) << 4);
    char* a_d0 = As + a_r * 128 + ((((a_q << 1))     ^ (a_r & 7)) << 4);
    char* a_d1 = As + a_r * 128 + ((((a_q << 1) | 1) ^ (a_r & 7)) << 4);

#define LA_H0(KT) do { const float* _p = Asrc + ((KT) << 6); \
    s0 = *(const float4*)_p; s1 = *(const float4*)(_p + 4); } while (0)
#define LA_H1(KT) do { const float* _p = Asrc + ((KT) << 6) + 8; \
    s0 = *(const float4*)_p; s1 = *(const float4*)(_p + 4); } while (0)
#define WA(D) do { bf16x8 _h; \
    _h[0]=(bf16)s0.x; _h[1]=(bf16)s0.y; _h[2]=(bf16)s0.z; _h[3]=(bf16)s0.w; \
    _h[4]=(bf16)s1.x; _h[5]=(bf16)s1.y; _h[6]=(bf16)s1.z; _h[7]=(bf16)s1.w; \
    *(bf16x8*)(D) = _h; } while (0)

#define RDA(XS) do { \
    _Pragma("unroll") \
    for (int m = 0; m < 4; ++m) \
        af[m] = *(const bf16x8*)(As + ((m << 4) + lr) * 128 + (XS)); \
} while (0)

#define RDB(XS) do { \
    _Pragma("unroll") \
    for (int n = 0; n < 4; ++n) \
        bf[n] = *(const bf16x8*)(Bs + (((wn << 6) + (n << 4) + lr)) * 128 + (XS)); \
} while (0)

#define MF16() do { \
    __builtin_amdgcn_s_setprio(1); \
    _Pragma("unroll") \
    for (int m = 0; m < 4; ++m) \
        _Pragma("unroll") \
        for (int n = 0; n < 4; ++n) \
            acc[m][n] = __builtin_amdgcn_mfma_f32_16x16x32_bf16(af[m], bf[n], acc[m][n], 0, 0, 0); \
    __builtin_amdgcn_s_setprio(0); \
} while (0)

#define VMCNT0() asm volatile("s_waitcnt vmcnt(0)" ::: "memory")
#define LGKM0()  asm volatile("s_waitcnt lgkmcnt(0)" ::: "memory")

    // ---------------- prologue: tile 0 ----------------
    LA_H0(0);
    WA(a_d0);                                     // auto-drains LA_H0
    LA_H1(0);
    stage_B128(Bsrc0, K, 0, Bs, t);
    stage_B128(Bsrc1, K, 0, Bs + 16384, t);
    WA(a_d1);                                     // auto vmcnt(8): SB stays in flight
    VMCNT0(); LGKM0();
    BAR();

    const int NT = K >> 6;                        // 16 K-tiles
    for (int kt = 0; kt < NT; ++kt) {
        const bool more = (kt + 1) < NT;
        if (more) LA_H0(kt + 1);                  // issue early: consumed post-BAR
        RDA(x0); RDB(x0);
        MF16();                                   // ks0
        RDA(x1); RDB(x1);
        LGKM0();                                  // this wave's LDS reads done
        BAR();                                    // all waves done: buffer free
        if (more) {
            WA(a_d0);                             // auto-drains LA_H0 (old, ~300cy)
            LA_H1(kt + 1);                        // reuse the 8-reg window
            stage_B128(Bsrc0, K, kt + 1, Bs, t);
            stage_B128(Bsrc1, K, kt + 1, Bs + 16384, t);
        }
        MF16();                                   // ks1 on regs; hides SB + LA_H1
        if (more) WA(a_d1);                       // auto vmcnt(8): SB in flight
        VMCNT0(); LGKM0();                        // SB landed + A-writes visible
        BAR();
    }

    // ---------------- epilogue: alpha * acc + bias ----------------
    const float alpha = *alphap;
    #pragma unroll
    for (int mf = 0; mf < 4; ++mf) {
        const int grow = bm0 + (mf << 4) + (hi << 2);
        #pragma unroll
        for (int nf = 0; nf < 4; ++nf) {
            const int gcol = bn0 + (wn << 6) + (nf << 4) + lr;
            const float bv = bias[gcol];
            #pragma unroll
            for (int r = 0; r < 4; ++r)
                C[(size_t)(grow + r) * N + gcol] = alpha * acc[mf][nf][r] + bv;
        }
    }
#undef LA_H0
#undef LA_H1
#undef WA
#undef RDA
#undef RDB
#undef MF16
#undef VMCNT0
#undef LGKM0
}

// ---------- fallback GEMM (round-1 proven): fp32 A staged in-kernel ----------
__global__ __launch_bounds__(256) void k_gemm_fb(const float* __restrict__ A,
                                                 const bf16* __restrict__ Bw,
                                                 const float* __restrict__ alphap,
                                                 const float* __restrict__ bias,
                                                 float* __restrict__ C,
                                                 int M, int N, int K) {
    __shared__ bf16 As[128 * 32];
    __shared__ bf16 Bs[128 * 32];
    const int t = threadIdx.x, lane = t & 63, wave = t >> 6;
    const int nbm = M >> 7;
    const int bm0 = (blockIdx.x % nbm) << 7;
    const int bn0 = (blockIdx.x / nbm) << 7;
    const int wr = (wave >> 1) << 6, wc = (wave & 1) << 6;
    f32x4 acc[4][4] = {};
    const int lr = lane & 15, lk = (lane >> 4) << 3;
    for (int k0 = 0; k0 < K; k0 += 32) {
        #pragma unroll
        for (int j = 0; j < 2; ++j) {
            const int c = t + j * 256;
            async_load16(Bw + (size_t)(bn0 + (c >> 2)) * K + k0 + ((c & 3) << 3),
                         (char*)Bs + j * 4096 + wave * 1024);
        }
        #pragma unroll
        for (int i = 0; i < 4; ++i) {
            const int idx = t + i * 256;
            const int row = idx >> 3, c4 = (idx & 7) << 2;
            const float4 v = *(const float4*)(A + (size_t)(bm0 + row) * K + k0 + c4);
            bf16x4 h;
            h[0] = (bf16)v.x; h[1] = (bf16)v.y; h[2] = (bf16)v.z; h[3] = (bf16)v.w;
            *(bf16x4*)(As + row * 32 + c4) = h;
        }
        __syncthreads();
        bf16x8 af[4], bfr[4];
        #pragma unroll
        for (int m = 0; m < 4; ++m) af[m] = *(const bf16x8*)(As + (wr + m * 16 + lr) * 32 + lk);
        #pragma unroll
        for (int n = 0; n < 4; ++n) bfr[n] = *(const bf16x8*)(Bs + (wc + n * 16 + lr) * 32 + lk);
        #pragma unroll
        for (int m = 0; m < 4; ++m)
            #pragma unroll
            for (int n = 0; n < 4; ++n)
                acc[m][n] = __builtin_amdgcn_mfma_f32_16x16x32_bf16(af[m], bfr[n], acc[m][n], 0, 0, 0);
        __syncthreads();
    }
    const float alpha = *alphap;
    #pragma unroll
    for (int m = 0; m < 4; ++m)
        #pragma unroll
        for (int n = 0; n < 4; ++n) {
            const int gcol = bn0 + wc + n * 16 + lr;
            const float bv = bias[gcol];
            #pragma unroll
            for (int r = 0; r < 4; ++r) {
                const int grow = bm0 + wr + m * 16 + ((lane >> 4) << 2) + r;
                C[(size_t)grow * N + gcol] = alpha * acc[m][n][r] + bv;
            }
        }
}

extern "C" void kernel_launch(void* const* d_in, const int* in_sizes, int n_in,
                              void* d_out, int out_size, void* d_ws, size_t ws_size,
                              hipStream_t stream) {
    const float* x     = (const float*)d_in[0];
    const float* wgt   = (const float*)d_in[1];
    const float* alpha = (const float*)d_in[2];
    const float* bias  = (const float*)d_in[3];
    float* out = (float*)d_out;

    const int wn   = in_sizes[1];        // 1048576
    const int dout = in_sizes[3];        // 1024
    const int din  = wn / dout;          // 1024
    const int m    = in_sizes[0] / din;  // 32768

    char* ws = (char*)d_ws;
    double* part = (double*)(ws + 64);          // 256 doubles
    bf16*   wt   = (bf16*)(ws + 8192);          // 2 MiB ternary weights

    k_abs_part<<<256, 256, 0, stream>>>(wgt, wn, part);
    k_quantW<<<512, 256, 0, stream>>>(wgt, part, wt, wn / 4, wn);

    const bool useF = (m % 64) == 0 && (dout % 256) == 0 && (din % 64) == 0 &&
                      ((m / 64) * (dout / 256)) % 8 == 0;
    if (useF) {
        dim3 grid((m / 64) * (dout / 256));
        k_gemmF<<<grid, 256, 0, stream>>>(x, wt, alpha, bias, out, m, dout, din);
    } else {
        dim3 grid((m / 128) * (dout / 128));
        k_gemm_fb<<<grid, 256, 0, stream>>>(x, wt, alpha, bias, out, m, dout, din);
    }
}